// Round 1
// baseline (138.671 us; speedup 1.0000x reference)
//
#include <hip/hip_runtime.h>

// TorchVQC: 8-qubit statevector sim, B=16384, D=256, fp32 complex.
// One wave (64 lanes) per batch element; lane holds 4 amplitudes s=(j<<6)|lane.
// Qubit k acts on state-bit P = 7-k. P>=6 -> register-local pair; P<6 -> shfl_xor(1<<P).

template<int P>
__device__ __forceinline__ void apply_gate(float (&sr)[4], float (&si)[4], int lane,
    float g00r, float g00i, float g01r, float g01i,
    float g10r, float g10i, float g11r, float g11i)
{
    if constexpr (P >= 6) {
        constexpr int jm = 1 << (P - 6);
        #pragma unroll
        for (int j = 0; j < 4; ++j) {
            if (j & jm) continue;
            const int j1 = j | jm;
            const float a0r = sr[j], a0i = si[j], a1r = sr[j1], a1i = si[j1];
            sr[j]  = g00r*a0r - g00i*a0i + g01r*a1r - g01i*a1i;
            si[j]  = g00r*a0i + g00i*a0r + g01r*a1i + g01i*a1r;
            sr[j1] = g10r*a0r - g10i*a0i + g11r*a1r - g11i*a1i;
            si[j1] = g10r*a0i + g10i*a0r + g11r*a1i + g11i*a1r;
        }
    } else {
        constexpr int m = 1 << P;
        const bool hi = (lane & m) != 0;
        // coefficient of own amplitude / of partner amplitude
        const float ar = hi ? g11r : g00r, ai = hi ? g11i : g00i;
        const float br = hi ? g10r : g01r, bi = hi ? g10i : g01i;
        #pragma unroll
        for (int j = 0; j < 4; ++j) {
            const float pr = __shfl_xor(sr[j], m, 64);
            const float pi = __shfl_xor(si[j], m, 64);
            const float orr = sr[j], oii = si[j];
            sr[j] = ar*orr - ai*oii + br*pr - bi*pi;
            si[j] = ar*oii + ai*orr + br*pi + bi*pr;
        }
    }
}

// CNOT: new[s] = old[s ^ (1<<PT)] if bit PC of s set, else old[s].
template<int PC, int PT>
__device__ __forceinline__ void apply_cnot(float (&sr)[4], float (&si)[4], int lane)
{
    constexpr int jt = (PT >= 6) ? (1 << (PT - 6)) : 0;
    constexpr int lt = (PT < 6) ? (1 << PT) : 0;
    float nr[4], ni[4];
    #pragma unroll
    for (int j = 0; j < 4; ++j) {
        const int jp = j ^ jt;
        float pr = sr[jp], pi = si[jp];
        if constexpr (lt != 0) {
            pr = __shfl_xor(pr, lt, 64);
            pi = __shfl_xor(pi, lt, 64);
        }
        bool ctrl;
        if constexpr (PC >= 6) ctrl = ((j >> (PC - 6)) & 1) != 0;
        else                   ctrl = ((lane >> PC) & 1) != 0;
        nr[j] = ctrl ? pr : sr[j];
        ni[j] = ctrl ? pi : si[j];
    }
    #pragma unroll
    for (int j = 0; j < 4; ++j) { sr[j] = nr[j]; si[j] = ni[j]; }
}

// Fused RZ(phi)*RY(theta) (reference applies RY then RZ). SCALE: 0.5 enc, 0.25 re-enc.
#define ENC_GATE(K, SCALE) do {                                         \
    const float th_ = theta[b * 8 + (K)] * (SCALE);                     \
    const float ph_ = phi[b * 8 + (K)] * (SCALE);                       \
    float c_, s_, cp_, sp_;                                             \
    __sincosf(th_, &s_, &c_);                                           \
    __sincosf(ph_, &sp_, &cp_);                                         \
    apply_gate<7 - (K)>(sr, si, lane,                                   \
        c_ * cp_, -c_ * sp_,  -s_ * cp_,  s_ * sp_,                     \
        s_ * cp_,  s_ * sp_,   c_ * cp_,  c_ * sp_);                    \
} while (0)

// Rot = RZ(om)*RY(th)*RZ(ph):
// g00 = c e^{-i(ph+om)/2}, g01 = -s e^{+i(ph-om)/2},
// g10 = s e^{-i(ph-om)/2}, g11 = c e^{+i(ph+om)/2}
#define ROT_GATE(L, K) do {                                             \
    const float* wp_ = w + ((L) * 8 + (K)) * 3;                         \
    const float wph_ = wp_[0], wth_ = wp_[1], wom_ = wp_[2];            \
    float c_, s_, ca_, sa_, cb_, sb_;                                   \
    __sincosf(wth_ * 0.5f, &s_, &c_);                                   \
    __sincosf(0.5f * (wph_ + wom_), &sa_, &ca_);                        \
    __sincosf(0.5f * (wph_ - wom_), &sb_, &cb_);                        \
    apply_gate<7 - (K)>(sr, si, lane,                                   \
        c_ * ca_, -c_ * sa_,  -s_ * cb_, -s_ * sb_,                     \
        s_ * cb_, -s_ * sb_,   c_ * ca_,  c_ * sa_);                    \
} while (0)

__global__ __launch_bounds__(256) void vqc_kernel(
    const float* __restrict__ theta,   // [B,8]
    const float* __restrict__ phi,     // [B,8]
    const float* __restrict__ jup,     // [B,28]
    const float* __restrict__ w,       // [2,8,3]
    float* __restrict__ out,           // [B,8]
    int Btot)
{
    const int tid  = blockIdx.x * blockDim.x + threadIdx.x;
    const int b    = tid >> 6;
    const int lane = threadIdx.x & 63;
    if (b >= Btot) return;

    float sr[4], si[4];
    #pragma unroll
    for (int j = 0; j < 4; ++j) { sr[j] = 0.f; si[j] = 0.f; }
    if (lane == 0) sr[0] = 1.f;

    // ---- encoding layer: RY(theta_k) then RZ(phi_k), fused ----
    ENC_GATE(0, 0.5f); ENC_GATE(1, 0.5f); ENC_GATE(2, 0.5f); ENC_GATE(3, 0.5f);
    ENC_GATE(4, 0.5f); ENC_GATE(5, 0.5f); ENC_GATE(6, 0.5f); ENC_GATE(7, 0.5f);

    // ---- IsingZZ diagonal phase ----
    // exponent(s) = (pi/2) * sum_p J_p * m_p(s),  m_p = -z_i z_j  (z = +1 if bit clear)
    // = -(pi/2) * ( J01 z0 z1 + z0*Q0 + z1*Q1 + base )
    {
        const float* Jb = jup + b * 28;
        float zq[8];
        #pragma unroll
        for (int q = 2; q < 8; ++q)
            zq[q] = ((lane >> (7 - q)) & 1) ? -1.f : 1.f;

        // pair order: (0,1),(0,2..7),(1,2..7),(2,3)...(6,7)
        const float J01 = Jb[0];
        float Q0 = 0.f, Q1 = 0.f, base = 0.f;
        int p = 1;
        #pragma unroll
        for (int x = 2; x < 8; ++x) { Q0 = fmaf(Jb[p], zq[x], Q0); ++p; }
        #pragma unroll
        for (int x = 2; x < 8; ++x) { Q1 = fmaf(Jb[p], zq[x], Q1); ++p; }
        #pragma unroll
        for (int i = 2; i < 8; ++i) {
            #pragma unroll
            for (int jx = i + 1; jx < 8; ++jx) {
                base = fmaf(Jb[p], zq[i] * zq[jx], base); ++p;
            }
        }

        constexpr float HPI = 1.5707963267948966f;
        #pragma unroll
        for (int j = 0; j < 4; ++j) {
            const float z0 = (j & 2) ? -1.f : 1.f;  // qubit 0 = s bit 7 = j bit 1
            const float z1 = (j & 1) ? -1.f : 1.f;  // qubit 1 = s bit 6 = j bit 0
            const float E = -HPI * (J01 * z0 * z1 + z0 * Q0 + z1 * Q1 + base);
            float ce, se;
            __sincosf(E, &se, &ce);
            const float r = sr[j], im = si[j];
            sr[j] = r * ce - im * se;
            si[j] = r * se + im * ce;
        }
    }

    // ---- layer 0: Rot gates, CNOT ring (range 1), re-encoding at half angles ----
    ROT_GATE(0, 0); ROT_GATE(0, 1); ROT_GATE(0, 2); ROT_GATE(0, 3);
    ROT_GATE(0, 4); ROT_GATE(0, 5); ROT_GATE(0, 6); ROT_GATE(0, 7);

    // l=0: ctrl k (bit 7-k), tgt (k+1)%8 (bit 7-(k+1)%8)
    apply_cnot<7, 6>(sr, si, lane);
    apply_cnot<6, 5>(sr, si, lane);
    apply_cnot<5, 4>(sr, si, lane);
    apply_cnot<4, 3>(sr, si, lane);
    apply_cnot<3, 2>(sr, si, lane);
    apply_cnot<2, 1>(sr, si, lane);
    apply_cnot<1, 0>(sr, si, lane);
    apply_cnot<0, 7>(sr, si, lane);

    ENC_GATE(0, 0.25f); ENC_GATE(1, 0.25f); ENC_GATE(2, 0.25f); ENC_GATE(3, 0.25f);
    ENC_GATE(4, 0.25f); ENC_GATE(5, 0.25f); ENC_GATE(6, 0.25f); ENC_GATE(7, 0.25f);

    // ---- layer 1: Rot gates, CNOT ring (range 2) ----
    ROT_GATE(1, 0); ROT_GATE(1, 1); ROT_GATE(1, 2); ROT_GATE(1, 3);
    ROT_GATE(1, 4); ROT_GATE(1, 5); ROT_GATE(1, 6); ROT_GATE(1, 7);

    apply_cnot<7, 5>(sr, si, lane);
    apply_cnot<6, 4>(sr, si, lane);
    apply_cnot<5, 3>(sr, si, lane);
    apply_cnot<4, 2>(sr, si, lane);
    apply_cnot<3, 1>(sr, si, lane);
    apply_cnot<2, 0>(sr, si, lane);
    apply_cnot<1, 7>(sr, si, lane);
    apply_cnot<0, 6>(sr, si, lane);

    // ---- readout: out[b,k] = sum_s |amp_s|^2 * (+1 if bit(7-k)==0 else -1) ----
    float p4[4];
    #pragma unroll
    for (int j = 0; j < 4; ++j) p4[j] = sr[j] * sr[j] + si[j] * si[j];
    const float v = p4[0] + p4[1] + p4[2] + p4[3];

    float o[8];
    o[0] = (p4[0] + p4[1]) - (p4[2] + p4[3]);  // qubit 0: sign from j bit 1
    o[1] = (p4[0] + p4[2]) - (p4[1] + p4[3]);  // qubit 1: sign from j bit 0
    #pragma unroll
    for (int q = 2; q < 8; ++q)
        o[q] = ((lane >> (7 - q)) & 1) ? -v : v;

    #pragma unroll
    for (int m = 1; m < 64; m <<= 1) {
        #pragma unroll
        for (int q = 0; q < 8; ++q) o[q] += __shfl_xor(o[q], m, 64);
    }

    if (lane == 0) {
        float4* op = reinterpret_cast<float4*>(out + b * 8);
        op[0] = make_float4(o[0], o[1], o[2], o[3]);
        op[1] = make_float4(o[4], o[5], o[6], o[7]);
    }
}

extern "C" void kernel_launch(void* const* d_in, const int* in_sizes, int n_in,
                              void* d_out, int out_size, void* d_ws, size_t ws_size,
                              hipStream_t stream) {
    const float* theta = (const float*)d_in[0];
    const float* phi   = (const float*)d_in[1];
    const float* jup   = (const float*)d_in[2];
    const float* w     = (const float*)d_in[3];
    float* out = (float*)d_out;

    const int B = in_sizes[0] / 8;          // 16384
    const int threads = 256;                // 4 waves/block, 1 batch elem per wave
    const int blocks = (B * 64 + threads - 1) / threads;
    hipLaunchKernelGGL(vqc_kernel, dim3(blocks), dim3(threads), 0, stream,
                       theta, phi, jup, w, out, B);
}